// Round 9
// baseline (157.905 us; speedup 1.0000x reference)
//
#include <hip/hip_runtime.h>
#include <hip/hip_bf16.h>
#include <math.h>

#define TOK 18432
#define EMB 512
#define NH 8
#define HD_ 64
#define HH 48
#define WW 48

typedef __attribute__((ext_vector_type(8))) __bf16 bf16x8;
typedef __attribute__((ext_vector_type(4))) float  f32x4;

__device__ __forceinline__ ushort f2bf(float x) {
    __hip_bfloat16 b = __float2bfloat16(x);
    return *(ushort*)&b;
}
__device__ __forceinline__ float bf2f(ushort u) {
    __hip_bfloat16 b = *(__hip_bfloat16*)&u;
    return __bfloat162float(b);
}

// async global->LDS, 16B per lane. LDS dest = wave-uniform base + lane*16 (linear).
__device__ __forceinline__ void gload16(const void* g, void* l) {
    __builtin_amdgcn_global_load_lds((const __attribute__((address_space(1))) void*)g,
                                     (__attribute__((address_space(3))) void*)l,
                                     16, 0, 0);
}

// builtin (NOT inline asm) so the hazard recognizer inserts MFMA->VALU nops.
__device__ __forceinline__ f32x4 mfma_bf16(bf16x8 a, bf16x8 b, f32x4 c) {
    return __builtin_amdgcn_mfma_f32_16x16x32_bf16(a, b, c, 0, 0, 0);
}

// ---------------- RoPE cos/sin tables: rows 0..7 = t, 8..55 = h, 56..103 = w
__global__ void fill_tabs(float2* __restrict__ tabs) {
    int idx = blockIdx.x * 256 + threadIdx.x;
    if (idx >= 104 * 10) return;
    int row = idx / 10, j = idx % 10;
    float base = fmaf((float)j, 127.0f / 9.0f, 1.0f) * 3.14159265358979323846f;
    float pos;
    if (row < 8)       pos = fmaf((float)row,        2.0f / 7.0f,  -1.0f);
    else if (row < 56) pos = fmaf((float)(row - 8),  2.0f / 47.0f, -1.0f);
    else               pos = fmaf((float)(row - 56), 2.0f / 47.0f, -1.0f);
    float f = pos * base;
    tabs[idx] = make_float2(cosf(f), sinf(f));
}

// ---------------- fp32 -> bf16 (hi only)
__global__ __launch_bounds__(256) void conv_hi(const float* __restrict__ src,
                                               ushort* __restrict__ dst, int n4) {
    int i = blockIdx.x * 256 + threadIdx.x;
    if (i >= n4) return;
    float4 v = ((const float4*)src)[i];
    ushort4 h = {f2bf(v.x), f2bf(v.y), f2bf(v.z), f2bf(v.w)};
    ((ushort4*)dst)[i] = h;
}

// ---------------- bf16 MFMA GEMM: C[M,N] = A[M,K] * B[N,K]^T.
// 256x256 tile, 512 threads (8 waves 2x4), BK=32, double-buffered LDS
// (4x16KB), ONE barrier per K-step. 64B LDS rows, chunk-slot swizzle
// ch ^ ((row>>1)&3): 0 bank conflicts (verified R8). Tile-traffic per
// block 512KB -> grid traffic halved vs 128^2 (the R8 L3-BW limiter).
template<int OUTBF>
__global__ __launch_bounds__(512, 2) void gemm_mfma(const ushort* __restrict__ Ah,
                                                    const ushort* __restrict__ Bh,
                                                    void* __restrict__ Cv,
                                                    int N, int K, int nbx) {
    __shared__ __align__(16) ushort As[2][256 * 32];
    __shared__ __align__(16) ushort Bs[2][256 * 32];
    int nwg = gridDim.x;
    int bid = blockIdx.x;
    int cpx = nwg >> 3;                       // grid % 8 == 0 guaranteed
    int swz = (bid & 7) * cpx + (bid >> 3);   // XCD-aware swizzle (bijective)
    int bm = (swz / nbx) * 256, bn = (swz % nbx) * 256;
    int tid = threadIdx.x;
    int lane = tid & 63, wave = tid >> 6;     // 8 waves
    int wr = wave >> 2, wc = wave & 3;        // 2 x 4 wave grid
    int fr = lane & 15, kg = lane >> 4;

    f32x4 acc[8][4];
#pragma unroll
    for (int m = 0; m < 8; ++m)
#pragma unroll
        for (int n = 0; n < 4; ++n) acc[m][n] = (f32x4){0.f, 0.f, 0.f, 0.f};

    // stage one 256x32 A-tile + B-tile into buffer `buf` (4 gloads/thread)
    auto stage = [&](int buf, int k0) {
#pragma unroll
        for (int it = 0; it < 2; ++it) {
            int f = it * 512 + tid;           // 0..1023
            int row = f >> 2, ch = f & 3;
            int sl = ch ^ ((row >> 1) & 3);   // inverse swizzle on SOURCE
            gload16(Ah + (size_t)(bm + row) * K + k0 + sl * 8, &As[buf][f * 8]);
            gload16(Bh + (size_t)(bn + row) * K + k0 + sl * 8, &Bs[buf][f * 8]);
        }
    };

    int nt = K >> 5;                          // K-steps of 32
    stage(0, 0);
    __syncthreads();
    int cur = 0;
    int ksw = (kg ^ ((fr >> 1) & 3)) * 8;     // swizzled chunk offset for reads
    for (int t = 0; t < nt; ++t) {
        if (t + 1 < nt) stage(cur ^ 1, (t + 1) << 5);   // prefetch under compute
        bf16x8 bh[4];
#pragma unroll
        for (int n = 0; n < 4; ++n)
            bh[n] = *(const bf16x8*)&Bs[cur][(wc * 64 + n * 16 + fr) * 32 + ksw];
#pragma unroll
        for (int m = 0; m < 8; ++m) {
            bf16x8 ah = *(const bf16x8*)&As[cur][(wr * 128 + m * 16 + fr) * 32 + ksw];
#pragma unroll
            for (int n = 0; n < 4; ++n)
                acc[m][n] = mfma_bf16(ah, bh[n], acc[m][n]);
        }
        __syncthreads();
        cur ^= 1;
    }
    // epilogue: C/D layout col=lane&15, row=(lane>>4)*4+i
#pragma unroll
    for (int m = 0; m < 8; ++m) {
        int row0 = bm + wr * 128 + m * 16 + kg * 4;
#pragma unroll
        for (int n = 0; n < 4; ++n) {
            int col = bn + wc * 64 + n * 16 + fr;
#pragma unroll
            for (int i = 0; i < 4; ++i) {
                if (OUTBF)
                    ((ushort*)Cv)[(size_t)(row0 + i) * N + col] = f2bf(acc[m][n][i]);
                else
                    ((float*)Cv)[(size_t)(row0 + i) * N + col] = acc[m][n][i];
            }
        }
    }
}

// ---------------- fused RMSnorm + RoPE on bf16 qkv -> bf16 q,k buffers.
// v stays in-place in qkvb (read directly by attn). q pre-scaled by HD^-0.5.
__global__ __launch_bounds__(256) void norm_rope_v3(const ushort* __restrict__ qkvb,
                                                    const float2* __restrict__ tabs,
                                                    const float* __restrict__ qw,
                                                    const float* __restrict__ kw,
                                                    ushort* __restrict__ qbf,
                                                    ushort* __restrict__ kbf) {
    int token = blockIdx.x;
    int lane = threadIdx.x & 63;
    int w = threadIdx.x >> 6;
    int t  = token / (HH * WW);
    int rem = token % (HH * WW);
    int xx = rem / WW;
    int yy = rem % WW;

    float2 cs = make_float2(1.f, 0.f);
    if (lane < 60) {
        int p = lane >> 1;
        int tr;
        if (p < 10)      tr = t * 10 + p;
        else if (p < 20) tr = (8 + xx) * 10 + (p - 10);
        else             tr = (56 + yy) * 10 + (p - 20);
        cs = tabs[tr];
    }
    float qwl = qw[lane], kwl = kw[lane];
#pragma unroll
    for (int hh = 0; hh < 2; ++hh) {
        int h = w * 2 + hh;
        const ushort* base = qkvb + (size_t)token * 1536 + h * 192;
        size_t ob = (size_t)token * 512 + h * 64 + lane;
#pragma unroll
        for (int qk = 0; qk < 2; ++qk) {
            float x = bf2f(base[qk * 64 + lane]);
            float ss = x * x;
#pragma unroll
            for (int o = 32; o; o >>= 1) ss += __shfl_xor(ss, o);
            float scale = rsqrtf(ss * (1.0f / 64.0f) + 1e-6f);
            float xn = x * scale * (qk ? kwl : qwl);
            float partner = __shfl_xor(xn, 1);
            float r = xn;
            if (lane < 60) {
                r = (lane & 1) ? fmaf(xn, cs.x,  partner * cs.y)
                               : fmaf(xn, cs.x, -partner * cs.y);
            }
            if (!qk) r *= 0.125f;   // fold HD^-0.5 into q (exact pow2)
            (qk ? kbf : qbf)[ob] = f2bf(r);
        }
    }
}

// ---------------- MFMA neighborhood attention: swapped operands,
// in-register lane-local masked softmax. Block = (2x2 patch, head).
// 32 q (8t x 2x2) x 128 k (8t x 4x4 window). V read in-place from qkvb.
__global__ __launch_bounds__(256) void attn_mfma(const ushort* __restrict__ qbf,
                                                 const ushort* __restrict__ kbf,
                                                 const ushort* __restrict__ qkvb,
                                                 ushort* __restrict__ ohi) {
    __shared__ __align__(16) char smem[45056];
    constexpr int Q_OFF = 0;       // [32 q][64 d] bf16, 128B rows, slot16 ^= row&7
    constexpr int K_OFF = 4096;    // [128 k][64 d] bf16, 128B rows, slot16 ^= row&7
    constexpr int V_OFF = 20480;   // [64 d][128 k] bf16, 256B rows, slot16 ^= d&7
    constexpr int P_OFF = 36864;   // [32 q][128 k] bf16, 256B rows, slot16 ^= q&7

    int patch = blockIdx.x, head = blockIdx.y;
    int bi = patch / 24, bj = patch % 24;
    int x0 = bi * 2, y0 = bj * 2;
    int ubx = min(max(x0 - 1, 0), 44), uby = min(max(y0 - 1, 0), 44);
    int tid = threadIdx.x, lane = tid & 63, w = tid >> 6;
    int fr = lane & 15, kg = lane >> 4;

    // ---- stage Q (1 gload/thread, pre-swizzled source chunk)
    {
        int f = tid;
        int row = f >> 3, sp = f & 7, sl = sp ^ (row & 7);
        int t = row >> 2, px = (row >> 1) & 1, py = row & 1;
        size_t tok = ((size_t)(t * HH + x0 + px)) * WW + (y0 + py);
        gload16(qbf + tok * 512 + head * 64 + sl * 8, smem + Q_OFF + f * 16);
    }
    // ---- stage K (4 gloads/thread)
#pragma unroll
    for (int it = 0; it < 4; ++it) {
        int f = it * 256 + tid;
        int row = f >> 3, sp = f & 7, sl = sp ^ (row & 7);
        int s = row >> 4, ki = (row >> 2) & 3, kj = row & 3;
        size_t tok = ((size_t)(s * HH + ubx + ki)) * WW + (uby + kj);
        gload16(kbf + tok * 512 + head * 64 + sl * 8, smem + K_OFF + f * 16);
    }
    // ---- stage V^T from qkvb (stride-1536 rows): register 4x4 transpose
#pragma unroll
    for (int it = 0; it < 2; ++it) {
        int u = it * 256 + tid;
        int sk = u >> 4, dg = u & 15;
        int s = sk >> 2, ki = sk & 3;
        ushort4 rv[4];
#pragma unroll
        for (int kj = 0; kj < 4; ++kj) {
            size_t tok = ((size_t)(s * HH + ubx + ki)) * WW + (uby + kj);
            rv[kj] = *(const ushort4*)(qkvb + tok * 1536 + head * 192 + 128 + dg * 4);
        }
        const ushort* rr = (const ushort*)rv;   // rr[kj*4 + dd]
#pragma unroll
        for (int dd = 0; dd < 4; ++dd) {
            int d = dg * 4 + dd;
            ushort4 val = {rr[dd], rr[4 + dd], rr[8 + dd], rr[12 + dd]};
            *(ushort4*)(smem + V_OFF + d * 256 + ((sk * 8) ^ ((d & 7) << 4))) = val;
        }
    }
    __syncthreads();

    // ---- QK^T swapped (S^T = K * Q^T) + in-register masked softmax: waves 0,1
    if (w < 2) {
        int q = w * 16 + fr;         // q = t*4 + px*2 + py
        bf16x8 qb[2];
#pragma unroll
        for (int ks = 0; ks < 2; ++ks)
            qb[ks] = *(const bf16x8*)(smem + Q_OFF + q * 128 +
                                      ((ks * 64 + kg * 16) ^ ((fr & 7) << 4)));
        f32x4 sc[8];
#pragma unroll
        for (int m = 0; m < 8; ++m) sc[m] = (f32x4){0.f, 0.f, 0.f, 0.f};
#pragma unroll
        for (int m = 0; m < 8; ++m)
#pragma unroll
            for (int ks = 0; ks < 2; ++ks) {
                bf16x8 a = *(const bf16x8*)(smem + K_OFF + (m * 16 + fr) * 128 +
                                            ((ks * 64 + kg * 16) ^ ((fr & 7) << 4)));
                sc[m] = mfma_bf16(a, qb[ks], sc[m]);
            }
        // lane holds S[k = m*16 + kg*4 + i][q]: s=m, ki=kg, kj=i
        int xq = x0 + ((q >> 1) & 1), yq = y0 + (q & 1);
        int lox = min(max(xq - 1, 0), 45) - ubx;
        int loy = min(max(yq - 1, 0), 45) - uby;
        bool vki = ((unsigned)(kg - lox)) <= 2u;
        float mx = -1e30f;
        if (vki) {
#pragma unroll
            for (int m = 0; m < 8; ++m)
#pragma unroll
                for (int i = 0; i < 4; ++i)
                    if (((unsigned)(i - loy)) <= 2u) mx = fmaxf(mx, sc[m][i]);
        }
        mx = fmaxf(mx, __shfl_xor(mx, 16));
        mx = fmaxf(mx, __shfl_xor(mx, 32));
        float sum = 0.f;
#pragma unroll
        for (int m = 0; m < 8; ++m)
#pragma unroll
            for (int i = 0; i < 4; ++i) {
                bool v = vki && (((unsigned)(i - loy)) <= 2u);
                float e = v ? __expf(sc[m][i] - mx) : 0.f;
                sc[m][i] = e;
                sum += e;
            }
        sum += __shfl_xor(sum, 16);
        sum += __shfl_xor(sum, 32);
        float inv = 1.0f / sum;
#pragma unroll
        for (int m = 0; m < 8; ++m) {
            ushort4 pk = {f2bf(sc[m][0] * inv), f2bf(sc[m][1] * inv),
                          f2bf(sc[m][2] * inv), f2bf(sc[m][3] * inv)};
            *(ushort4*)(smem + P_OFF + q * 256 +
                        ((m * 32 + kg * 8) ^ ((q & 7) << 4))) = pk;
        }
    }
    __syncthreads();

    // ---- PV swapped (out^T = V^T * P^T): wave w owns d-tile w
    f32x4 ov[2];
    ov[0] = (f32x4){0.f, 0.f, 0.f, 0.f};
    ov[1] = (f32x4){0.f, 0.f, 0.f, 0.f};
#pragma unroll
    for (int kb = 0; kb < 4; ++kb) {
        bf16x8 a = *(const bf16x8*)(smem + V_OFF + (w * 16 + fr) * 256 +
                                    ((kb * 64 + kg * 16) ^ ((fr & 7) << 4)));
#pragma unroll
        for (int nt2 = 0; nt2 < 2; ++nt2) {
            bf16x8 b = *(const bf16x8*)(smem + P_OFF + (nt2 * 16 + fr) * 256 +
                                        ((kb * 64 + kg * 16) ^ ((fr & 7) << 4)));
            ov[nt2] = mfma_bf16(a, b, ov[nt2]);
        }
    }
    // ---- epilogue: lane holds out^T[d = w*16+kg*4+i][q = nt2*16+fr]
#pragma unroll
    for (int nt2 = 0; nt2 < 2; ++nt2) {
        int q = nt2 * 16 + fr;
        int t = q >> 2, px = (q >> 1) & 1, py = q & 1;
        size_t tok = ((size_t)(t * HH + x0 + px)) * WW + (y0 + py);
        size_t ob = tok * 512 + head * 64 + w * 16 + kg * 4;
        ushort4 hv = {f2bf(ov[nt2][0]), f2bf(ov[nt2][1]),
                      f2bf(ov[nt2][2]), f2bf(ov[nt2][3])};
        *(ushort4*)&ohi[ob] = hv;
    }
}

extern "C" void kernel_launch(void* const* d_in, const int* in_sizes, int n_in,
                              void* d_out, int out_size, void* d_ws, size_t ws_size,
                              hipStream_t stream) {
    const float* x     = (const float*)d_in[0];
    const float* w_qkv = (const float*)d_in[1];
    const float* w_out = (const float*)d_in[2];
    const float* qnw   = (const float*)d_in[3];
    const float* knw   = (const float*)d_in[4];
    float* out = (float*)d_out;
    char*  ws  = (char*)d_ws;

    const size_t QKVB_B = (size_t)TOK * 1536 * 2;   // 56,623,104  (bf16 qkv)
    const size_t TABS_B = 16384;
    const size_t WQ_B   = (size_t)1536 * 512 * 2;   // 1,572,864
    const size_t WO_B   = (size_t)512 * 512 * 2;    //   524,288

    // ws layout: qkvb | tabs | wqhi | wohi | ohi
    ushort* qkvb = (ushort*)ws;
    float2* tabs = (float2*)(ws + QKVB_B);
    ushort* wqhi = (ushort*)(ws + QKVB_B + TABS_B);
    ushort* wohi = wqhi + (size_t)1536 * 512;
    ushort* ohi  = (ushort*)(ws + QKVB_B + TABS_B + WQ_B + WO_B);

    // d_out region (75.5 MB) multiplexed over time:
    //   phase 1: xhi (bf16 x, 37.7 MB)            [written by conv, read by gemm1]
    //   phase 2: qbf | kbf (2 x 18.9 MB = 75.5)   [overwrite xhi after gemm1]
    //   phase 3: final fp32 out                    [gemm2 overwrites everything]
    ushort* xhi = (ushort*)d_out;
    ushort* qbf = (ushort*)d_out;
    ushort* kbf = qbf + (size_t)TOK * 512;

    fill_tabs<<<5, 256, 0, stream>>>(tabs);
    conv_hi<<<(TOK * 512 / 4 + 255) / 256, 256, 0, stream>>>(x, xhi, TOK * 512 / 4);
    conv_hi<<<(1536 * 512 / 4 + 255) / 256, 256, 0, stream>>>(w_qkv, wqhi, 1536 * 512 / 4);
    conv_hi<<<(512 * 512 / 4 + 255) / 256, 256, 0, stream>>>(w_out, wohi, 512 * 512 / 4);

    // qkv(bf16) = x @ w_qkv^T   (256^2 tiles: 72 x 6 = 432 blocks)
    gemm_mfma<1><<<(TOK / 256) * (1536 / 256), 512, 0, stream>>>(
        xhi, wqhi, qkvb, 1536, 512, 1536 / 256);
    norm_rope_v3<<<TOK, 256, 0, stream>>>(qkvb, tabs, qnw, knw, qbf, kbf);
    attn_mfma<<<dim3(576, NH), 256, 0, stream>>>(qbf, kbf, qkvb, ohi);
    // out(fp32) = o @ w_out^T   (256^2 tiles: 72 x 2 = 144 blocks)
    gemm_mfma<0><<<(TOK / 256) * (512 / 256), 512, 0, stream>>>(
        ohi, wohi, out, 512, 512, 512 / 256);
}

// Round 10
// 135.025 us; speedup vs baseline: 1.1694x; 1.1694x over previous
//
#include <hip/hip_runtime.h>
#include <hip/hip_bf16.h>
#include <math.h>

#define TOK 18432
#define EMB 512
#define NH 8
#define HD_ 64
#define HH 48
#define WW 48

typedef __attribute__((ext_vector_type(8))) __bf16 bf16x8;
typedef __attribute__((ext_vector_type(4))) float  f32x4;

__device__ __forceinline__ ushort f2bf(float x) {
    __hip_bfloat16 b = __float2bfloat16(x);
    return *(ushort*)&b;
}
__device__ __forceinline__ float bf2f(ushort u) {
    __hip_bfloat16 b = *(__hip_bfloat16*)&u;
    return __bfloat162float(b);
}

// async global->LDS, 16B per lane. LDS dest = wave-uniform base + lane*16 (linear).
__device__ __forceinline__ void gload16(const void* g, void* l) {
    __builtin_amdgcn_global_load_lds((const __attribute__((address_space(1))) void*)g,
                                     (__attribute__((address_space(3))) void*)l,
                                     16, 0, 0);
}

// builtin (NOT inline asm) so the hazard recognizer inserts MFMA->VALU nops.
__device__ __forceinline__ f32x4 mfma_bf16(bf16x8 a, bf16x8 b, f32x4 c) {
    return __builtin_amdgcn_mfma_f32_16x16x32_bf16(a, b, c, 0, 0, 0);
}

// ---------------- RoPE cos/sin tables: rows 0..7 = t, 8..55 = h, 56..103 = w
__global__ void fill_tabs(float2* __restrict__ tabs) {
    int idx = blockIdx.x * 256 + threadIdx.x;
    if (idx >= 104 * 10) return;
    int row = idx / 10, j = idx % 10;
    float base = fmaf((float)j, 127.0f / 9.0f, 1.0f) * 3.14159265358979323846f;
    float pos;
    if (row < 8)       pos = fmaf((float)row,        2.0f / 7.0f,  -1.0f);
    else if (row < 56) pos = fmaf((float)(row - 8),  2.0f / 47.0f, -1.0f);
    else               pos = fmaf((float)(row - 56), 2.0f / 47.0f, -1.0f);
    float f = pos * base;
    tabs[idx] = make_float2(cosf(f), sinf(f));
}

// ---------------- fp32 -> bf16 (hi only)
__global__ __launch_bounds__(256) void conv_hi(const float* __restrict__ src,
                                               ushort* __restrict__ dst, int n4) {
    int i = blockIdx.x * 256 + threadIdx.x;
    if (i >= n4) return;
    float4 v = ((const float4*)src)[i];
    ushort4 h = {f2bf(v.x), f2bf(v.y), f2bf(v.z), f2bf(v.w)};
    ((ushort4*)dst)[i] = h;
}

// ---------------- fused QKV GEMM + RMSnorm + RoPE epilogue.
// C = x @ w_qkv^T (M=TOK, N=1536, K=512). 128x128 tile, BK=32, dbuf LDS,
// one barrier/K-step, swizzle = R8 proven (0 conflicts). Each wave owns a
// 64-row x 64-col quadrant; 64-col groups are exactly one of q/k/v of one
// head (1536 = 8 heads x {q,k,v} x 64). Epilogue does rmsnorm (4 reg adds +
// shfl_xor 1/2/4/8 over fr) + RoPE (partner = shfl_xor(xn,1)) in-register
// and writes bf16 qbf/kbf/vbf directly -- norm_rope kernel + qkv buffer gone.
__global__ __launch_bounds__(256) void gemm_qkv(const ushort* __restrict__ Ah,
                                                const ushort* __restrict__ Bh,
                                                const float2* __restrict__ tabs,
                                                const float* __restrict__ qnw,
                                                const float* __restrict__ knw,
                                                ushort* __restrict__ qbf,
                                                ushort* __restrict__ kbf,
                                                ushort* __restrict__ vbf) {
    const int N = 1536, K = 512, nbx = 12;
    __shared__ __align__(16) ushort As[2][128 * 32];
    __shared__ __align__(16) ushort Bs[2][128 * 32];
    int nwg = gridDim.x;
    int bid = blockIdx.x;
    int cpx = nwg >> 3;
    int swz = (bid & 7) * cpx + (bid >> 3);
    int bm = (swz / nbx) * 128, bn = (swz % nbx) * 128;
    int tid = threadIdx.x;
    int lane = tid & 63, wave = tid >> 6;
    int wr = wave >> 1, wc = wave & 1;
    int fr = lane & 15, kg = lane >> 4;

    f32x4 acc[4][4];
#pragma unroll
    for (int m = 0; m < 4; ++m)
#pragma unroll
        for (int n = 0; n < 4; ++n) acc[m][n] = (f32x4){0.f, 0.f, 0.f, 0.f};

    auto stage = [&](int buf, int k0) {
#pragma unroll
        for (int it = 0; it < 2; ++it) {
            int f = it * 256 + tid;
            int row = f >> 2, ch = f & 3;
            int sl = ch ^ ((row >> 1) & 3);
            gload16(Ah + (size_t)(bm + row) * K + k0 + sl * 8, &As[buf][f * 8]);
            gload16(Bh + (size_t)(bn + row) * K + k0 + sl * 8, &Bs[buf][f * 8]);
        }
    };

    int nt = K >> 5;
    stage(0, 0);
    __syncthreads();
    int cur = 0;
    int ksw = (kg ^ ((fr >> 1) & 3)) * 8;
    for (int t = 0; t < nt; ++t) {
        if (t + 1 < nt) stage(cur ^ 1, (t + 1) << 5);
        bf16x8 bh[4];
#pragma unroll
        for (int n = 0; n < 4; ++n)
            bh[n] = *(const bf16x8*)&Bs[cur][(wc * 64 + n * 16 + fr) * 32 + ksw];
#pragma unroll
        for (int m = 0; m < 4; ++m) {
            bf16x8 ah = *(const bf16x8*)&As[cur][(wr * 64 + m * 16 + fr) * 32 + ksw];
#pragma unroll
            for (int n = 0; n < 4; ++n)
                acc[m][n] = mfma_bf16(ah, bh[n], acc[m][n]);
        }
        __syncthreads();
        cur ^= 1;
    }

    // ---- fused epilogue. wave's 64-col group: g = bn/64 + wc
    int g = (bn >> 6) + wc;
    int type = g % 3;        // 0=q, 1=k, 2=v
    int h = g / 3;
    if (type == 2) {
#pragma unroll
        for (int m = 0; m < 4; ++m)
#pragma unroll
            for (int i = 0; i < 4; ++i) {
                int token = bm + wr * 64 + m * 16 + kg * 4 + i;
#pragma unroll
                for (int n = 0; n < 4; ++n)
                    vbf[(size_t)token * 512 + h * 64 + n * 16 + fr] = f2bf(acc[m][n][i]);
            }
    } else {
        const float* wptr = type ? knw : qnw;
        ushort* obuf = type ? kbf : qbf;
        float qsc = type ? 1.0f : 0.125f;    // fold HD^-0.5 into q
        float wv[4];
#pragma unroll
        for (int n = 0; n < 4; ++n) wv[n] = wptr[n * 16 + fr];
#pragma unroll
        for (int m = 0; m < 4; ++m)
#pragma unroll
            for (int i = 0; i < 4; ++i) {
                // rmsnorm over the 64-d row (4 regs x 16 fr-lanes)
                float s = 0.f;
#pragma unroll
                for (int n = 0; n < 4; ++n) s = fmaf(acc[m][n][i], acc[m][n][i], s);
                s += __shfl_xor(s, 1); s += __shfl_xor(s, 2);
                s += __shfl_xor(s, 4); s += __shfl_xor(s, 8);
                float inv = rsqrtf(s * (1.0f / 64.0f) + 1e-6f);
                int token = bm + wr * 64 + m * 16 + kg * 4 + i;
                int t = token / (HH * WW);
                int rem = token % (HH * WW);
                int xx = rem / WW, yy = rem % WW;
#pragma unroll
                for (int n = 0; n < 4; ++n) {
                    float xn = acc[m][n][i] * inv * wv[n];
                    float partner = __shfl_xor(xn, 1);
                    int dc = n * 16 + fr;
                    float r;
                    if (dc < 60) {
                        int p = dc >> 1;
                        int tr = (p < 10) ? t * 10 + p
                               : (p < 20) ? (8 + xx) * 10 + (p - 10)
                                          : (56 + yy) * 10 + (p - 20);
                        float2 cs = tabs[tr];
                        r = (dc & 1) ? fmaf(xn, cs.x,  partner * cs.y)
                                     : fmaf(xn, cs.x, -partner * cs.y);
                    } else {
                        r = xn;
                    }
                    obuf[(size_t)token * 512 + h * 64 + dc] = f2bf(r * qsc);
                }
            }
    }
}

// ---------------- bf16 MFMA GEMM (R8 proven config): C = A @ B^T, fp32 out.
// 128x128 tile, BK=32, dbuf LDS (2x16KB), one barrier/K-step, 0 conflicts.
__global__ __launch_bounds__(256) void gemm_mfma(const ushort* __restrict__ Ah,
                                                 const ushort* __restrict__ Bh,
                                                 float* __restrict__ C,
                                                 int N, int K, int nbx) {
    __shared__ __align__(16) ushort As[2][128 * 32];
    __shared__ __align__(16) ushort Bs[2][128 * 32];
    int nwg = gridDim.x;
    int bid = blockIdx.x;
    int cpx = nwg >> 3;
    int swz = (bid & 7) * cpx + (bid >> 3);
    int bm = (swz / nbx) * 128, bn = (swz % nbx) * 128;
    int tid = threadIdx.x;
    int lane = tid & 63, wave = tid >> 6;
    int wr = wave >> 1, wc = wave & 1;
    int fr = lane & 15, kg = lane >> 4;

    f32x4 acc[4][4];
#pragma unroll
    for (int m = 0; m < 4; ++m)
#pragma unroll
        for (int n = 0; n < 4; ++n) acc[m][n] = (f32x4){0.f, 0.f, 0.f, 0.f};

    auto stage = [&](int buf, int k0) {
#pragma unroll
        for (int it = 0; it < 2; ++it) {
            int f = it * 256 + tid;
            int row = f >> 2, ch = f & 3;
            int sl = ch ^ ((row >> 1) & 3);
            gload16(Ah + (size_t)(bm + row) * K + k0 + sl * 8, &As[buf][f * 8]);
            gload16(Bh + (size_t)(bn + row) * K + k0 + sl * 8, &Bs[buf][f * 8]);
        }
    };

    int nt = K >> 5;
    stage(0, 0);
    __syncthreads();
    int cur = 0;
    int ksw = (kg ^ ((fr >> 1) & 3)) * 8;
    for (int t = 0; t < nt; ++t) {
        if (t + 1 < nt) stage(cur ^ 1, (t + 1) << 5);
        bf16x8 bh[4];
#pragma unroll
        for (int n = 0; n < 4; ++n)
            bh[n] = *(const bf16x8*)&Bs[cur][(wc * 64 + n * 16 + fr) * 32 + ksw];
#pragma unroll
        for (int m = 0; m < 4; ++m) {
            bf16x8 ah = *(const bf16x8*)&As[cur][(wr * 64 + m * 16 + fr) * 32 + ksw];
#pragma unroll
            for (int n = 0; n < 4; ++n)
                acc[m][n] = mfma_bf16(ah, bh[n], acc[m][n]);
        }
        __syncthreads();
        cur ^= 1;
    }
#pragma unroll
    for (int m = 0; m < 4; ++m) {
        int row0 = bm + wr * 64 + m * 16 + kg * 4;
#pragma unroll
        for (int n = 0; n < 4; ++n) {
            int col = bn + wc * 64 + n * 16 + fr;
#pragma unroll
            for (int i = 0; i < 4; ++i)
                C[(size_t)(row0 + i) * N + col] = acc[m][n][i];
        }
    }
}

// ---------------- MFMA neighborhood attention: swapped operands,
// in-register lane-local masked softmax. Block = (2x2 patch, head).
// 32 q (8t x 2x2) x 128 k (8t x 4x4 window). V from compact vbf.
__global__ __launch_bounds__(256) void attn_mfma(const ushort* __restrict__ qbf,
                                                 const ushort* __restrict__ kbf,
                                                 const ushort* __restrict__ vbf,
                                                 ushort* __restrict__ ohi) {
    __shared__ __align__(16) char smem[45056];
    constexpr int Q_OFF = 0;       // [32 q][64 d] bf16, 128B rows, slot16 ^= row&7
    constexpr int K_OFF = 4096;    // [128 k][64 d] bf16, 128B rows, slot16 ^= row&7
    constexpr int V_OFF = 20480;   // [64 d][128 k] bf16, 256B rows, slot16 ^= d&7
    constexpr int P_OFF = 36864;   // [32 q][128 k] bf16, 256B rows, slot16 ^= q&7

    int patch = blockIdx.x, head = blockIdx.y;
    int bi = patch / 24, bj = patch % 24;
    int x0 = bi * 2, y0 = bj * 2;
    int ubx = min(max(x0 - 1, 0), 44), uby = min(max(y0 - 1, 0), 44);
    int tid = threadIdx.x, lane = tid & 63, w = tid >> 6;
    int fr = lane & 15, kg = lane >> 4;

    // ---- stage Q (1 gload/thread, pre-swizzled source chunk)
    {
        int f = tid;
        int row = f >> 3, sp = f & 7, sl = sp ^ (row & 7);
        int t = row >> 2, px = (row >> 1) & 1, py = row & 1;
        size_t tok = ((size_t)(t * HH + x0 + px)) * WW + (y0 + py);
        gload16(qbf + tok * 512 + head * 64 + sl * 8, smem + Q_OFF + f * 16);
    }
    // ---- stage K (4 gloads/thread)
#pragma unroll
    for (int it = 0; it < 4; ++it) {
        int f = it * 256 + tid;
        int row = f >> 3, sp = f & 7, sl = sp ^ (row & 7);
        int s = row >> 4, ki = (row >> 2) & 3, kj = row & 3;
        size_t tok = ((size_t)(s * HH + ubx + ki)) * WW + (uby + kj);
        gload16(kbf + tok * 512 + head * 64 + sl * 8, smem + K_OFF + f * 16);
    }
    // ---- stage V^T from vbf: register 4x4 transpose, b64 swizzled writes
#pragma unroll
    for (int it = 0; it < 2; ++it) {
        int u = it * 256 + tid;
        int sk = u >> 4, dg = u & 15;
        int s = sk >> 2, ki = sk & 3;
        ushort4 rv[4];
#pragma unroll
        for (int kj = 0; kj < 4; ++kj) {
            size_t tok = ((size_t)(s * HH + ubx + ki)) * WW + (uby + kj);
            rv[kj] = *(const ushort4*)(vbf + tok * 512 + head * 64 + dg * 4);
        }
        const ushort* rr = (const ushort*)rv;   // rr[kj*4 + dd]
#pragma unroll
        for (int dd = 0; dd < 4; ++dd) {
            int d = dg * 4 + dd;
            ushort4 val = {rr[dd], rr[4 + dd], rr[8 + dd], rr[12 + dd]};
            *(ushort4*)(smem + V_OFF + d * 256 + ((sk * 8) ^ ((d & 7) << 4))) = val;
        }
    }
    __syncthreads();

    // ---- QK^T swapped (S^T = K * Q^T) + in-register masked softmax: waves 0,1
    if (w < 2) {
        int q = w * 16 + fr;         // q = t*4 + px*2 + py
        bf16x8 qb[2];
#pragma unroll
        for (int ks = 0; ks < 2; ++ks)
            qb[ks] = *(const bf16x8*)(smem + Q_OFF + q * 128 +
                                      ((ks * 64 + kg * 16) ^ ((fr & 7) << 4)));
        f32x4 sc[8];
#pragma unroll
        for (int m = 0; m < 8; ++m) sc[m] = (f32x4){0.f, 0.f, 0.f, 0.f};
#pragma unroll
        for (int m = 0; m < 8; ++m)
#pragma unroll
            for (int ks = 0; ks < 2; ++ks) {
                bf16x8 a = *(const bf16x8*)(smem + K_OFF + (m * 16 + fr) * 128 +
                                            ((ks * 64 + kg * 16) ^ ((fr & 7) << 4)));
                sc[m] = mfma_bf16(a, qb[ks], sc[m]);
            }
        // lane holds S[k = m*16 + kg*4 + i][q]: s=m, ki=kg, kj=i
        int xq = x0 + ((q >> 1) & 1), yq = y0 + (q & 1);
        int lox = min(max(xq - 1, 0), 45) - ubx;
        int loy = min(max(yq - 1, 0), 45) - uby;
        bool vki = ((unsigned)(kg - lox)) <= 2u;
        float mx = -1e30f;
        if (vki) {
#pragma unroll
            for (int m = 0; m < 8; ++m)
#pragma unroll
                for (int i = 0; i < 4; ++i)
                    if (((unsigned)(i - loy)) <= 2u) mx = fmaxf(mx, sc[m][i]);
        }
        mx = fmaxf(mx, __shfl_xor(mx, 16));
        mx = fmaxf(mx, __shfl_xor(mx, 32));
        float sum = 0.f;
#pragma unroll
        for (int m = 0; m < 8; ++m)
#pragma unroll
            for (int i = 0; i < 4; ++i) {
                bool v = vki && (((unsigned)(i - loy)) <= 2u);
                float e = v ? __expf(sc[m][i] - mx) : 0.f;
                sc[m][i] = e;
                sum += e;
            }
        sum += __shfl_xor(sum, 16);
        sum += __shfl_xor(sum, 32);
        float inv = 1.0f / sum;
#pragma unroll
        for (int m = 0; m < 8; ++m) {
            ushort4 pk = {f2bf(sc[m][0] * inv), f2bf(sc[m][1] * inv),
                          f2bf(sc[m][2] * inv), f2bf(sc[m][3] * inv)};
            *(ushort4*)(smem + P_OFF + q * 256 +
                        ((m * 32 + kg * 8) ^ ((q & 7) << 4))) = pk;
        }
    }
    __syncthreads();

    // ---- PV swapped (out^T = V^T * P^T): wave w owns d-tile w
    f32x4 ov[2];
    ov[0] = (f32x4){0.f, 0.f, 0.f, 0.f};
    ov[1] = (f32x4){0.f, 0.f, 0.f, 0.f};
#pragma unroll
    for (int kb = 0; kb < 4; ++kb) {
        bf16x8 a = *(const bf16x8*)(smem + V_OFF + (w * 16 + fr) * 256 +
                                    ((kb * 64 + kg * 16) ^ ((fr & 7) << 4)));
#pragma unroll
        for (int nt2 = 0; nt2 < 2; ++nt2) {
            bf16x8 b = *(const bf16x8*)(smem + P_OFF + (nt2 * 16 + fr) * 256 +
                                        ((kb * 64 + kg * 16) ^ ((fr & 7) << 4)));
            ov[nt2] = mfma_bf16(a, b, ov[nt2]);
        }
    }
    // ---- epilogue: lane holds out^T[d = w*16+kg*4+i][q = nt2*16+fr]
#pragma unroll
    for (int nt2 = 0; nt2 < 2; ++nt2) {
        int q = nt2 * 16 + fr;
        int t = q >> 2, px = (q >> 1) & 1, py = q & 1;
        size_t tok = ((size_t)(t * HH + x0 + px)) * WW + (y0 + py);
        size_t ob = tok * 512 + head * 64 + w * 16 + kg * 4;
        ushort4 hv = {f2bf(ov[nt2][0]), f2bf(ov[nt2][1]),
                      f2bf(ov[nt2][2]), f2bf(ov[nt2][3])};
        *(ushort4*)&ohi[ob] = hv;
    }
}

extern "C" void kernel_launch(void* const* d_in, const int* in_sizes, int n_in,
                              void* d_out, int out_size, void* d_ws, size_t ws_size,
                              hipStream_t stream) {
    const float* x     = (const float*)d_in[0];
    const float* w_qkv = (const float*)d_in[1];
    const float* w_out = (const float*)d_in[2];
    const float* qnw   = (const float*)d_in[3];
    const float* knw   = (const float*)d_in[4];
    float* out = (float*)d_out;
    char*  ws  = (char*)d_ws;

    const size_t TABS_B = 16384;
    const size_t WQ_B   = (size_t)1536 * 512 * 2;   // 1,572,864
    const size_t WO_B   = (size_t)512 * 512 * 2;    //   524,288
    const size_t QBF_B  = (size_t)TOK * 512 * 2;    // 18,874,368

    // ws layout: tabs | wqhi | wohi | qbf | kbf | vbf | ohi  (~77.6 MB)
    float2* tabs = (float2*)ws;
    ushort* wqhi = (ushort*)(ws + TABS_B);
    ushort* wohi = wqhi + (size_t)1536 * 512;
    ushort* qbf  = (ushort*)(ws + TABS_B + WQ_B + WO_B);
    ushort* kbf  = qbf + (size_t)TOK * 512;
    ushort* vbf  = kbf + (size_t)TOK * 512;
    ushort* ohi  = vbf + (size_t)TOK * 512;

    // d_out: phase 1 = xhi (bf16 x, 37.7 MB); phase 2 = final fp32 out.
    ushort* xhi = (ushort*)d_out;

    fill_tabs<<<5, 256, 0, stream>>>(tabs);
    conv_hi<<<(TOK * 512 / 4 + 255) / 256, 256, 0, stream>>>(x, xhi, TOK * 512 / 4);
    conv_hi<<<(1536 * 512 / 4 + 255) / 256, 256, 0, stream>>>(w_qkv, wqhi, 1536 * 512 / 4);
    conv_hi<<<(512 * 512 / 4 + 255) / 256, 256, 0, stream>>>(w_out, wohi, 512 * 512 / 4);

    // fused: qkv GEMM + rmsnorm + rope -> qbf/kbf/vbf (144 x 12 = 1728 blocks)
    gemm_qkv<<<(TOK / 128) * (1536 / 128), 256, 0, stream>>>(
        xhi, wqhi, tabs, qnw, knw, qbf, kbf, vbf);
    attn_mfma<<<dim3(576, NH), 256, 0, stream>>>(qbf, kbf, vbf, ohi);
    // out(fp32) = o @ w_out^T
    gemm_mfma<<<(TOK / 128) * (512 / 128), 256, 0, stream>>>(
        ohi, wohi, out, 512, 512, 512 / 128);
}